// Round 9
// baseline (24611.594 us; speedup 1.0000x reference)
//
#include <hip/hip_runtime.h>

// Per-channel LSTM (input_size=1) + per-channel Linear(H,1), fully fused.
// B=512, T=1024, C=64, H=128.
// Round 9: HW never co-schedules 2 of our 512-thread blocks (R3-R7), so the
// 512-block grid ran as TWO sequential passes with only 2 waves/SIMD each.
// Fix: merge two 64-row blocks into ONE 1024-thread block (16 waves = 2
// independent row-groups x 8 col-slices). Grid=256 -> exactly 1 block/CU,
// single pass, 4 waves/SIMD: per-step barrier/stall cost paid 1024x (not
// 2048x) and doubled wave residency hides dep-chain + barrier-drain latency.
// Each group: own ping-pong hbuf (2x16 KB); shared block barrier, 1/step.
// Body = R7 slim path (merged gate rcp, per-cell tanh rcp, LDS x stage).

typedef _Float16 half8 __attribute__((ext_vector_type(8)));
typedef float floatx4 __attribute__((ext_vector_type(4)));

#define LOG2E 1.44269504088896340736f

__global__ __launch_bounds__(1024, 1) void lstm_fused(
    const float* __restrict__ x,    // [B,T,C]
    const float* __restrict__ Wih,  // [C,4H]
    const float* __restrict__ Whh,  // [C,4H,H]
    const float* __restrict__ bih,  // [C,4H]
    const float* __restrict__ bhh,  // [C,4H]
    const float* __restrict__ Wfc,  // [C,H]
    const float* __restrict__ bfc,  // [C]
    float* __restrict__ out)        // [B,C]
{
    constexpr int T = 1024, C = 64, H = 128, G = 512;
    constexpr int TC = T * C;

    // Per-group ping-pong h buffers: [group][parity][4 rt][4 ks][64 chunks][8 f16]
    __shared__ _Float16 hbuf[2][2][8192];   // 64 KB
    // x stage: [parity][128 rows] (1 KB)
    __shared__ float xs[2][128];

    const int bid = blockIdx.x;
    const int ch  = bid & 63;            // channel
    const int b0  = (bid >> 6) << 7;     // batch base: 0,128,256,384

    const int tid  = threadIdx.x;
    const int wave = tid >> 6;           // 0..15
    const int g    = wave >> 3;          // row-group 0/1 (rows b0+g*64 ..)
    const int w    = wave & 7;           // col-slice: hidden cols [w*16, w*16+16)
    const int l    = tid & 63;
    const int q    = l >> 4;             // quad
    const int li   = l & 15;

    // ---- per-lane constants: W_ih, bias, W_hh fragments in registers ----
    // (same channel for both groups -> duplicated, fine)
    float wihr[4], bias[4];
    half8 Wf[4][4];
#pragma unroll
    for (int ct = 0; ct < 4; ++ct) {
        const float sc = (ct == 2) ? 2.0f * LOG2E : LOG2E;  // gate order i,f,g,o
        const int col = ct * H + w * 16 + li;
        wihr[ct] = Wih[ch * G + col] * sc;
        bias[ct] = (bih[ch * G + col] + bhh[ch * G + col]) * sc;
#pragma unroll
        for (int ks = 0; ks < 4; ++ks) {
            const float* wp = &Whh[((size_t)(ch * G + col)) * H + ks * 32 + q * 8];
            half8 hv;
#pragma unroll
            for (int j = 0; j < 8; ++j) hv[j] = (_Float16)(wp[j] * sc);
            Wf[ct][ks] = hv;
        }
    }

    // zero t=0 read buffers (h0 = 0): each group's 512 threads zero its 16 KB
    {
        const int gtid = tid & 511;
        for (int i = gtid; i < 8192; i += 512) hbuf[g][0][i] = (_Float16)0.0f;
    }

    // x loader: threads 0..127 each own one batch row of this block
    const float* xrow = x + (size_t)(b0 + (tid & 127)) * TC + ch;
    if (tid < 128) xs[0][tid] = xrow[0];  // t = 0

    // cell state (fp32 registers): 4 rowtiles x 4 rows
    float cst[4][4];
#pragma unroll
    for (int rt = 0; rt < 4; ++rt)
#pragma unroll
        for (int r = 0; r < 4; ++r) cst[rt][r] = 0.0f;

    // ---- h layout with XOR bank swizzle (per group) ----
    // value (row m in 16-rowtile, hidden hh): ks=hh>>5, qq=(hh&31)>>3, j=hh&7
    // chunk c = qq*16 + (m ^ (qq&3)); element = (rt*4+ks)*512 + c*8 + j
    const int ks_w = w >> 1;
    const int qq_w = ((w & 1) << 1) + (li >> 3);
    const int j_w  = li & 7;
    const int rxor = qq_w & 3;
    int wel[4];
#pragma unroll
    for (int r = 0; r < 4; ++r)
        wel[r] = ks_w * 512 + (qq_w * 16 + q * 4 + (r ^ rxor)) * 8 + j_w;
    // read: lane l wants chunk (qq=q, m=li) -> c = q*16 + (li ^ (q&3))
    const int rdoff = (q * 16 + (li ^ (q & 3))) * 8;

    __syncthreads();

    for (int t = 0; t < T; ++t) {
        const _Float16* __restrict__ rb = hbuf[g][t & 1];
        _Float16* __restrict__ wb = hbuf[g][(t & 1) ^ 1];
        const float* __restrict__ xcur = &xs[t & 1][g * 64];

        // prefetch next step's x early (hidden behind compute)
        const int tn = (t + 1 < T) ? t + 1 : T - 1;
        float xpre;
        if (tid < 128) xpre = xrow[tn * C];

#pragma unroll
        for (int rt = 0; rt < 4; ++rt) {
            // x for this rowtile's 4 rows: one b128 broadcast read
            const floatx4 xq = *(const floatx4*)&xcur[rt * 16 + q * 4];

            // init acc with x*W_ih + bias (one fma each)
            floatx4 acc[4];
#pragma unroll
            for (int ct = 0; ct < 4; ++ct)
#pragma unroll
                for (int r = 0; r < 4; ++r)
                    acc[ct][r] = fmaf(xq[r], wihr[ct], bias[ct]);

            // one A-fragment live at a time: ds_read_b128 then its 4 MFMAs
#pragma unroll
            for (int ks = 0; ks < 4; ++ks) {
                const half8 a = *(const half8*)&rb[(rt * 4 + ks) * 512 + rdoff];
#pragma unroll
                for (int ct = 0; ct < 4; ++ct)
                    acc[ct] = __builtin_amdgcn_mfma_f32_16x16x32_f16(a, Wf[ct][ks], acc[ct], 0, 0, 0);
            }

            // activations: one rcp for all 4 gate denominators, one rcp for
            // tanh(c). Preacts prescaled by log2e (g by 2*log2e).
#pragma unroll
            for (int r = 0; r < 4; ++r) {
                const float u  = __builtin_amdgcn_exp2f(-acc[0][r]);
                const float v  = __builtin_amdgcn_exp2f(-acc[1][r]);
                const float p  = __builtin_amdgcn_exp2f(acc[2][r]);
                const float wq = __builtin_amdgcn_exp2f(-acc[3][r]);
                const float Du = 1.0f + u, Dv = 1.0f + v;
                const float Dp = 1.0f + p, Dw = 1.0f + wq;
                const float A  = Du * Dv, Bq = Dp * Dw;
                const float R  = __builtin_amdgcn_rcpf(A * Bq);
                const float RA = R * Bq;                      // 1/(Du*Dv)
                const float RB = R * A;                       // 1/(Dp*Dw)
                const float ig = Dv * RA;                     // sigmoid(i)
                const float fg = Du * RA;                     // sigmoid(f)
                const float tg = fmaf(-2.0f, Dw * RB, 1.0f);  // tanh(g)
                const float og = Dp * RB;                     // sigmoid(o)
                const float cn = fmaf(fg, cst[rt][r], ig * tg);
                cst[rt][r] = cn;
                // tanh(cn): clamp exp2 arg to +-29 (tanh saturates to 1.0f)
                const float tq = __builtin_amdgcn_fmed3f(
                    cn * (2.0f * LOG2E), -29.0f, 29.0f);
                const float hq = fmaf(-2.0f,
                    __builtin_amdgcn_rcpf(1.0f + __builtin_amdgcn_exp2f(tq)), 1.0f);
                wb[rt * 2048 + wel[r]] = (_Float16)(og * hq);
            }
        }

        // publish next step's x, then the per-step barrier
        if (tid < 128) xs[(t + 1) & 1][tid] = xpre;
        __syncthreads();
    }

    // ---- epilogue: out[b0+row, ch] = h_final . Wfc[ch] + bfc[ch] ----
    // T even -> final h in parity buffer 0 of each group.
    if (tid < 128) {
        const int g2 = tid >> 6;
        const int rr = tid & 63;
        const int rt = rr >> 4, m = rr & 15;
        float s = bfc[ch];
#pragma unroll
        for (int hh = 0; hh < H; ++hh) {
            const int ks = hh >> 5, qq = (hh & 31) >> 3, j = hh & 7;
            const int c = qq * 16 + (m ^ (qq & 3));
            s += (float)hbuf[g2][0][(rt * 4 + ks) * 512 + c * 8 + j] * Wfc[ch * H + hh];
        }
        out[(size_t)(b0 + tid) * C + ch] = s;
    }
}

extern "C" void kernel_launch(void* const* d_in, const int* in_sizes, int n_in,
                              void* d_out, int out_size, void* d_ws, size_t ws_size,
                              hipStream_t stream) {
    const float* x   = (const float*)d_in[0];
    const float* Wih = (const float*)d_in[1];
    const float* Whh = (const float*)d_in[2];
    const float* bih = (const float*)d_in[3];
    const float* bhh = (const float*)d_in[4];
    const float* Wfc = (const float*)d_in[5];
    const float* bfc = (const float*)d_in[6];
    float* out = (float*)d_out;

    lstm_fused<<<256, 1024, 0, stream>>>(x, Wih, Whh, bih, bhh, Wfc, bfc, out);
}

// Round 10
// 6757.462 us; speedup vs baseline: 3.6421x; 3.6421x over previous
//
#include <hip/hip_runtime.h>

// Per-channel LSTM (input_size=1) + per-channel Linear(H,1), fully fused.
// B=512, T=1024, C=64, H=128.
// Round 10: R1-R9 establish 1 block/CU is unavoidable (2nd block co-resides
// only at VGPR<=64, which our 64-reg weight set can't meet without spilling).
// At that point VALUBusy+MfmaUtil ~= 92%: the kernel is VALU-ISSUE-bound.
// Fix: express the entire cell update as floatx4 elementwise arithmetic so
// the backend emits 2-wide packed f32 ops (v_pk_fma_f32 / v_pk_mul_f32 /
// v_pk_add_f32, gfx90a+) — halves regular-VALU issue. Transcendentals
// (5 exp2 + 2 rcp per cell) remain scalar (no packed trans).
// Base structure = R6 (best, 6098us): grid=512x512thr, ping-pong 32KB hbuf,
// XOR swizzle, register x prefetch, 1 barrier/step. launch_bounds(512,1)
// gives the allocator 256-reg headroom for vector temps (R8: no spill).

typedef _Float16 half8 __attribute__((ext_vector_type(8)));
typedef float floatx4 __attribute__((ext_vector_type(4)));

#define LOG2E 1.44269504088896340736f

__global__ __launch_bounds__(512, 1) void lstm_fused(
    const float* __restrict__ x,    // [B,T,C]
    const float* __restrict__ Wih,  // [C,4H]
    const float* __restrict__ Whh,  // [C,4H,H]
    const float* __restrict__ bih,  // [C,4H]
    const float* __restrict__ bhh,  // [C,4H]
    const float* __restrict__ Wfc,  // [C,H]
    const float* __restrict__ bfc,  // [C]
    float* __restrict__ out)        // [B,C]
{
    constexpr int T = 1024, C = 64, H = 128, G = 512;
    constexpr int TC = T * C;

    // Two h buffers: [4 rowtiles][4 ksteps][64 chunks][8 f16] = 16 KB each.
    __shared__ _Float16 hbuf[2][8192];

    const int bid = blockIdx.x;
    const int ch  = bid & 63;          // channel
    const int b0  = (bid >> 6) << 6;   // batch tile base: 0,64,...,448

    const int tid = threadIdx.x;
    const int w   = tid >> 6;          // wave 0..7 -> hidden slice [w*16, w*16+16)
    const int l   = tid & 63;
    const int q   = l >> 4;            // quad
    const int li  = l & 15;

    // ---- per-lane constants: W_ih, bias, W_hh fragments in registers ----
    float wihr[4], bias[4];
    half8 Wf[4][4];
#pragma unroll
    for (int ct = 0; ct < 4; ++ct) {
        const float sc = (ct == 2) ? 2.0f * LOG2E : LOG2E;  // gate order i,f,g,o
        const int col = ct * H + w * 16 + li;
        wihr[ct] = Wih[ch * G + col] * sc;
        bias[ct] = (bih[ch * G + col] + bhh[ch * G + col]) * sc;
#pragma unroll
        for (int ks = 0; ks < 4; ++ks) {
            const float* wp = &Whh[((size_t)(ch * G + col)) * H + ks * 32 + q * 8];
            half8 hv;
#pragma unroll
            for (int j = 0; j < 8; ++j) hv[j] = (_Float16)(wp[j] * sc);
            Wf[ct][ks] = hv;
        }
    }

    // zero t=0 read buffer (h0 = 0)
    for (int i = tid; i < 8192; i += 512) hbuf[0][i] = (_Float16)0.0f;

    // cell state (fp32 registers, vector form): 4 rowtiles x 4 rows
    floatx4 cstv[4];
#pragma unroll
    for (int rt = 0; rt < 4; ++rt) cstv[rt] = (floatx4){0.0f, 0.0f, 0.0f, 0.0f};

    // ---- h layout with XOR bank swizzle ----
    const int ks_w = w >> 1;
    const int qq_w = ((w & 1) << 1) + (li >> 3);
    const int j_w  = li & 7;
    const int rxor = qq_w & 3;
    int wel[4];
#pragma unroll
    for (int r = 0; r < 4; ++r)
        wel[r] = ks_w * 512 + (qq_w * 16 + q * 4 + (r ^ rxor)) * 8 + j_w;
    const int rdoff = (q * 16 + (li ^ (q & 3))) * 8;

    // ---- x addressing: uniform base pointer + per-lane 32-bit offset ----
    const float* xb = x + ch;
    const int rb0 = (b0 + q * 4) * TC;

    floatx4 xv[4];
#pragma unroll
    for (int rt = 0; rt < 4; ++rt)
#pragma unroll
        for (int r = 0; r < 4; ++r)
            xv[rt][r] = xb[rb0 + (rt * 16 + r) * TC];  // t = 0

    const float* xnp   = xb + C;              // next-step base (t=1)
    const float* xlast = xb + (T - 1) * C;

    __syncthreads();

    const floatx4 one   = {1.0f, 1.0f, 1.0f, 1.0f};
    const floatx4 ntwo  = {-2.0f, -2.0f, -2.0f, -2.0f};
    const floatx4 clo   = {-29.0f, -29.0f, -29.0f, -29.0f};
    const floatx4 chi   = {29.0f, 29.0f, 29.0f, 29.0f};
    const floatx4 two_l = {2.0f * LOG2E, 2.0f * LOG2E, 2.0f * LOG2E, 2.0f * LOG2E};

    auto step = [&](const _Float16* __restrict__ rb, _Float16* __restrict__ wb) {
#pragma unroll
        for (int rt = 0; rt < 4; ++rt) {
            // init acc with x*W_ih + bias (packed fma)
            floatx4 acc[4];
#pragma unroll
            for (int ct = 0; ct < 4; ++ct) {
                const floatx4 wsp = {wihr[ct], wihr[ct], wihr[ct], wihr[ct]};
                const floatx4 bsp = {bias[ct], bias[ct], bias[ct], bias[ct]};
                acc[ct] = __builtin_elementwise_fma(xv[rt], wsp, bsp);
            }

            // one A-fragment live at a time: ds_read_b128 then its 4 MFMAs
#pragma unroll
            for (int ks = 0; ks < 4; ++ks) {
                const half8 a = *(const half8*)&rb[(rt * 4 + ks) * 512 + rdoff];
#pragma unroll
                for (int ct = 0; ct < 4; ++ct)
                    acc[ct] = __builtin_amdgcn_mfma_f32_16x16x32_f16(a, Wf[ct][ks], acc[ct], 0, 0, 0);
            }

            // ---- activations: vectorized (v_pk_*_f32), scalar trans only ----
            floatx4 u, v, p, wq;
#pragma unroll
            for (int e = 0; e < 4; ++e) {
                u[e]  = __builtin_amdgcn_exp2f(-acc[0][e]);
                v[e]  = __builtin_amdgcn_exp2f(-acc[1][e]);
                p[e]  = __builtin_amdgcn_exp2f(acc[2][e]);
                wq[e] = __builtin_amdgcn_exp2f(-acc[3][e]);
            }
            const floatx4 Du = u + one, Dv = v + one, Dp = p + one, Dw = wq + one;
            const floatx4 A  = Du * Dv, Bq = Dp * Dw;
            const floatx4 AB = A * Bq;
            floatx4 R;
#pragma unroll
            for (int e = 0; e < 4; ++e) R[e] = __builtin_amdgcn_rcpf(AB[e]);
            const floatx4 RA = R * Bq;                 // 1/(Du*Dv)
            const floatx4 RB = R * A;                  // 1/(Dp*Dw)
            const floatx4 ig = Dv * RA;                // sigmoid(i)
            const floatx4 fg = Du * RA;                // sigmoid(f)
            const floatx4 tg = __builtin_elementwise_fma(ntwo, Dw * RB, one);  // tanh(g)
            const floatx4 og = Dp * RB;                // sigmoid(o)
            const floatx4 cn = __builtin_elementwise_fma(fg, cstv[rt], ig * tg);
            cstv[rt] = cn;
            // tanh(cn): clamp exp2 arg to +-29 (tanh saturates to 1.0f)
            floatx4 tq = cn * two_l;
            tq = __builtin_elementwise_min(__builtin_elementwise_max(tq, clo), chi);
            floatx4 Eq;
#pragma unroll
            for (int e = 0; e < 4; ++e) Eq[e] = __builtin_amdgcn_exp2f(tq[e]);
            const floatx4 Dq = Eq + one;
            floatx4 iq;
#pragma unroll
            for (int e = 0; e < 4; ++e) iq[e] = __builtin_amdgcn_rcpf(Dq[e]);
            const floatx4 hv4 = og * __builtin_elementwise_fma(ntwo, iq, one);
#pragma unroll
            for (int r = 0; r < 4; ++r)
                wb[rt * 2048 + wel[r]] = (_Float16)hv4[r];
        }

        // reload xv for the NEXT step (same registers -> prefetch across barrier)
#pragma unroll
        for (int rt = 0; rt < 4; ++rt)
#pragma unroll
            for (int r = 0; r < 4; ++r)
                xv[rt][r] = xnp[rb0 + (rt * 16 + r) * TC];

        __syncthreads();
    };

    for (int t = 0; t < T; t += 2) {
        step(hbuf[0], hbuf[1]);
        xnp = (xnp == xlast) ? xnp : xnp + C;
        step(hbuf[1], hbuf[0]);
        xnp = (xnp == xlast) ? xnp : xnp + C;
    }

    // ---- epilogue: out[b0+row, ch] = h_final . Wfc[ch] + bfc[ch] ----
    // T even -> final h is in hbuf[0]; last __syncthreads already done.
    if (tid < 64) {
        const int row = tid;
        const int rt = row >> 4, m = row & 15;
        float s = bfc[ch];
#pragma unroll
        for (int hh = 0; hh < H; ++hh) {
            const int ks = hh >> 5, qq = (hh & 31) >> 3, j = hh & 7;
            const int c = qq * 16 + (m ^ (qq & 3));
            s += (float)hbuf[0][(rt * 4 + ks) * 512 + c * 8 + j] * Wfc[ch * H + hh];
        }
        out[(size_t)(b0 + row) * C + ch] = s;
    }
}

extern "C" void kernel_launch(void* const* d_in, const int* in_sizes, int n_in,
                              void* d_out, int out_size, void* d_ws, size_t ws_size,
                              hipStream_t stream) {
    const float* x   = (const float*)d_in[0];
    const float* Wih = (const float*)d_in[1];
    const float* Whh = (const float*)d_in[2];
    const float* bih = (const float*)d_in[3];
    const float* bhh = (const float*)d_in[4];
    const float* Wfc = (const float*)d_in[5];
    const float* bfc = (const float*)d_in[6];
    float* out = (float*)d_out;

    lstm_fused<<<512, 512, 0, stream>>>(x, Wih, Whh, bih, bhh, Wfc, bfc, out);
}